// Round 5
// baseline (325.304 us; speedup 1.0000x reference)
//
#include <hip/hip_runtime.h>
#include <math.h>

// Masked sparsemax, one wave per row, 32 elems/lane in registers.
// Michelot active-set iteration seeded at theta0 = rowmax - 1:
// since p_max = z_max - theta* <= 1, theta* >= M-1, so {z > M-1} (size ~14
// for Gaussian rows) is already a superset of the support -> ~2-3 iterations
// instead of ~10 from the full-set seed. For theta_t <= theta*, the update
// theta += (sum_{z>theta}(z-theta) - 1)/count is monotone non-decreasing and
// bounded by theta*, so the count-stable break is an exact fixed point.

constexpr int D     = 2048;
constexpr int LANES = 64;
constexpr int VPL   = D / 4 / LANES;   // float4 vectors per lane = 8
constexpr int RPB   = 4;               // rows (waves) per 256-thread block
constexpr int TPB   = RPB * LANES;

typedef __attribute__((ext_vector_type(4))) float nfloat4;

__global__ __launch_bounds__(TPB) void sparsemax_kernel(
    const float* __restrict__ x,
    const int*   __restrict__ mask,
    float*       __restrict__ out)
{
    const int    wid  = threadIdx.x >> 6;
    const int    lane = threadIdx.x & 63;
    const size_t row  = (size_t)blockIdx.x * RPB + wid;
    const size_t rb   = row * D;

    const float4* __restrict__ xv = (const float4*)(x    + rb);
    const int4*   __restrict__ mv = (const int4*)  (mask + rb);
    nfloat4*      __restrict__ ov = (nfloat4*)     (out  + rb);

    // Interleaved layout: lane stride 16 B -> each load instr covers 1 KiB.
    float z[4 * VPL];
    float M = -INFINITY;               // row max over active entries
    #pragma unroll
    for (int i = 0; i < VPL; ++i) {
        const float4 a = xv[i * LANES + lane];
        const int4   m = mv[i * LANES + lane];
        z[4*i + 0] = m.x ? a.x : -INFINITY;
        z[4*i + 1] = m.y ? a.y : -INFINITY;
        z[4*i + 2] = m.z ? a.z : -INFINITY;
        z[4*i + 3] = m.w ? a.w : -INFINITY;
        M = fmaxf(M, fmaxf(fmaxf(z[4*i+0], z[4*i+1]),
                           fmaxf(z[4*i+2], z[4*i+3])));
    }
    #pragma unroll
    for (int off = 32; off > 0; off >>= 1)
        M = fmaxf(M, __shfl_xor(M, off, 64));

    float theta;
    if (M == -INFINITY) {
        theta = INFINITY;              // all-masked row -> all zeros
    } else {
        theta = M - 1.0f;              // lower bound on theta*
        int prevC = -1;
        for (int it = 0; it < 32; ++it) {
            // 4 independent accumulators to shorten the dependency chain.
            float s0 = 0.f, s1 = 0.f, s2 = 0.f, s3 = 0.f;
            int c = 0;                 // wave-uniform via ballot+popc (SALU)
            #pragma unroll
            for (int k = 0; k < 4 * VPL; k += 4) {
                const float d0 = z[k+0] - theta;
                const float d1 = z[k+1] - theta;
                const float d2 = z[k+2] - theta;
                const float d3 = z[k+3] - theta;
                s0 += fmaxf(d0, 0.f);
                s1 += fmaxf(d1, 0.f);
                s2 += fmaxf(d2, 0.f);
                s3 += fmaxf(d3, 0.f);
                c += __popcll(__ballot(d0 > 0.f));
                c += __popcll(__ballot(d1 > 0.f));
                c += __popcll(__ballot(d2 > 0.f));
                c += __popcll(__ballot(d3 > 0.f));
            }
            if (c == prevC || c == 0) break;   // set stable -> theta exact
            float s = (s0 + s1) + (s2 + s3);
            #pragma unroll
            for (int off = 32; off > 0; off >>= 1)
                s += __shfl_xor(s, off, 64);
            theta += (s - 1.0f) / (float)c;
            prevC = c;
        }
    }

    // p = max(z - theta, 0); masked lanes (z = -inf) give exactly 0.
    #pragma unroll
    for (int i = 0; i < VPL; ++i) {
        nfloat4 o;
        o.x = fmaxf(z[4*i + 0] - theta, 0.0f);
        o.y = fmaxf(z[4*i + 1] - theta, 0.0f);
        o.z = fmaxf(z[4*i + 2] - theta, 0.0f);
        o.w = fmaxf(z[4*i + 3] - theta, 0.0f);
        __builtin_nontemporal_store(o, &ov[i * LANES + lane]);
    }
}

extern "C" void kernel_launch(void* const* d_in, const int* in_sizes, int n_in,
                              void* d_out, int out_size, void* d_ws, size_t ws_size,
                              hipStream_t stream) {
    const float* x    = (const float*)d_in[0];
    const int*   mask = (const int*)  d_in[1];
    float*       out  = (float*)d_out;
    const int n_rows = in_sizes[0] / D;
    sparsemax_kernel<<<n_rows / RPB, TPB, 0, stream>>>(x, mask, out);
}

// Round 6
// 322.544 us; speedup vs baseline: 1.0086x; 1.0086x over previous
//
#include <hip/hip_runtime.h>
#include <math.h>

// Masked sparsemax, one wave per row, 32 elems/lane in registers.
// Michelot active-set iteration seeded at theta0 = rowmax - 1 (support
// superset ~14 elems for Gaussian rows -> ~2-3 iterations, exact fixed point).
//
// Round-6 fix: LOAD PHASE SEPARATED FROM CONSUME PHASE. Rounds 1-5 sat at
// ~134 us (2 TB/s) regardless of compute because VGPR_Count=40..48 forced the
// compiler to batch the 16 per-wave loads (load 2-3, waitcnt, consume, repeat)
// -> ~6 exposed HBM latencies per wave with only ~3 waves/SIMD to hide them.
// Now all 8 x-float4 + 8 mask-int4 loads issue back-to-back into registers
// (needs ~64 live VGPRs), allowed by __launch_bounds__(256, 4) (cap 128).

constexpr int D     = 2048;
constexpr int LANES = 64;
constexpr int VPL   = D / 4 / LANES;   // float4 vectors per lane = 8
constexpr int RPB   = 4;               // rows (waves) per 256-thread block
constexpr int TPB   = RPB * LANES;

typedef __attribute__((ext_vector_type(4))) float nfloat4;

__global__ __launch_bounds__(TPB, 4) void sparsemax_kernel(
    const float* __restrict__ x,
    const int*   __restrict__ mask,
    float*       __restrict__ out)
{
    const int    wid  = threadIdx.x >> 6;
    const int    lane = threadIdx.x & 63;
    const size_t row  = (size_t)blockIdx.x * RPB + wid;
    const size_t rb   = row * D;

    const float4* __restrict__ xv = (const float4*)(x    + rb);
    const int4*   __restrict__ mv = (const int4*)  (mask + rb);
    nfloat4*      __restrict__ ov = (nfloat4*)     (out  + rb);

    // ---- Load phase: issue ALL 16 vector loads before any consumption.
    float4 a[VPL];
    int4   m[VPL];
    #pragma unroll
    for (int i = 0; i < VPL; ++i) a[i] = xv[i * LANES + lane];
    #pragma unroll
    for (int i = 0; i < VPL; ++i) m[i] = mv[i * LANES + lane];

    // ---- Consume: masked z + row max.
    float z[4 * VPL];
    float M = -INFINITY;
    #pragma unroll
    for (int i = 0; i < VPL; ++i) {
        z[4*i + 0] = m[i].x ? a[i].x : -INFINITY;
        z[4*i + 1] = m[i].y ? a[i].y : -INFINITY;
        z[4*i + 2] = m[i].z ? a[i].z : -INFINITY;
        z[4*i + 3] = m[i].w ? a[i].w : -INFINITY;
        M = fmaxf(M, fmaxf(fmaxf(z[4*i+0], z[4*i+1]),
                           fmaxf(z[4*i+2], z[4*i+3])));
    }
    #pragma unroll
    for (int off = 32; off > 0; off >>= 1)
        M = fmaxf(M, __shfl_xor(M, off, 64));

    float theta;
    if (M == -INFINITY) {
        theta = INFINITY;              // all-masked row -> all zeros
    } else {
        theta = M - 1.0f;              // lower bound on theta*
        int prevC = -1;
        for (int it = 0; it < 32; ++it) {
            float s0 = 0.f, s1 = 0.f, s2 = 0.f, s3 = 0.f;
            int c = 0;                 // wave-uniform via ballot+popc (SALU)
            #pragma unroll
            for (int k = 0; k < 4 * VPL; k += 4) {
                const float d0 = z[k+0] - theta;
                const float d1 = z[k+1] - theta;
                const float d2 = z[k+2] - theta;
                const float d3 = z[k+3] - theta;
                s0 += fmaxf(d0, 0.f);
                s1 += fmaxf(d1, 0.f);
                s2 += fmaxf(d2, 0.f);
                s3 += fmaxf(d3, 0.f);
                c += __popcll(__ballot(d0 > 0.f));
                c += __popcll(__ballot(d1 > 0.f));
                c += __popcll(__ballot(d2 > 0.f));
                c += __popcll(__ballot(d3 > 0.f));
            }
            if (c == prevC || c == 0) break;   // set stable -> theta exact
            float s = (s0 + s1) + (s2 + s3);
            #pragma unroll
            for (int off = 32; off > 0; off >>= 1)
                s += __shfl_xor(s, off, 64);
            theta += (s - 1.0f) / (float)c;
            prevC = c;
        }
    }

    // p = max(z - theta, 0); masked lanes (z = -inf) give exactly 0.
    #pragma unroll
    for (int i = 0; i < VPL; ++i) {
        nfloat4 o;
        o.x = fmaxf(z[4*i + 0] - theta, 0.0f);
        o.y = fmaxf(z[4*i + 1] - theta, 0.0f);
        o.z = fmaxf(z[4*i + 2] - theta, 0.0f);
        o.w = fmaxf(z[4*i + 3] - theta, 0.0f);
        __builtin_nontemporal_store(o, &ov[i * LANES + lane]);
    }
}

extern "C" void kernel_launch(void* const* d_in, const int* in_sizes, int n_in,
                              void* d_out, int out_size, void* d_ws, size_t ws_size,
                              hipStream_t stream) {
    const float* x    = (const float*)d_in[0];
    const int*   mask = (const int*)  d_in[1];
    float*       out  = (float*)d_out;
    const int n_rows = in_sizes[0] / D;
    sparsemax_kernel<<<n_rows / RPB, TPB, 0, stream>>>(x, mask, out);
}